// Round 1
// baseline (2825.539 us; speedup 1.0000x reference)
//
#include <hip/hip_runtime.h>
#include <math.h>

#define BB 32
#define NN 1025
#define DDIM 768
#define HH 12
#define DH 64
#define KC 257
#define CPBH 32

// ---------------------------------------------------------------------------
// Kernel 1: tiled softmax pooling -> ctx [B, KC, D]
//   block = 64 threads (1 wave), grid = B*KC; blockIdx: b*KC + kk
//   kk==0: copy register row x[b,0,:]; else pool tile t=kk-1.
// ---------------------------------------------------------------------------
__global__ __launch_bounds__(64) void pool_ctx_kernel(const float* __restrict__ x,
                                                      const float* __restrict__ wlog,
                                                      float* __restrict__ ctx) {
  const int bid = blockIdx.x;
  const int b = bid / KC;
  const int kk = bid % KC;
  const int lane = threadIdx.x;
  const float* xb = x + (size_t)b * NN * DDIM;
  float* cout = ctx + ((size_t)b * KC + kk) * DDIM;
  if (kk == 0) {
    const float4* src = (const float4*)xb;  // row 0
    float4* dst = (float4*)cout;
#pragma unroll
    for (int i = 0; i < 3; i++) dst[lane + 64 * i] = src[lane + 64 * i];
    return;
  }
  const int t = kk - 1;
  const int gy = t >> 4, gx = t & 15;
  // rows: 1 + (2gy+iy)*32 + 2gx+ix for s=iy*2+ix -> offsets 0,1,32,33 from r0
  const int r0 = 1 + gy * 64 + gx * 2;
  const float* xr0 = xb + (size_t)r0 * DDIM;
  float s0 = 0.f, s1 = 0.f, s2 = 0.f, s3 = 0.f;
  for (int c = lane; c < DDIM; c += 64) {
    const float w = wlog[c];
    s0 = fmaf(xr0[c], w, s0);
    s1 = fmaf(xr0[c + DDIM], w, s1);
    s2 = fmaf(xr0[c + 32 * DDIM], w, s2);
    s3 = fmaf(xr0[c + 33 * DDIM], w, s3);
  }
#pragma unroll
  for (int off = 32; off; off >>= 1) {
    s0 += __shfl_xor(s0, off);
    s1 += __shfl_xor(s1, off);
    s2 += __shfl_xor(s2, off);
    s3 += __shfl_xor(s3, off);
  }
  const float m = fmaxf(fmaxf(s0, s1), fmaxf(s2, s3));
  float e0 = expf(s0 - m), e1 = expf(s1 - m), e2 = expf(s2 - m), e3 = expf(s3 - m);
  const float inv = 1.0f / (e0 + e1 + e2 + e3);
  e0 *= inv; e1 *= inv; e2 *= inv; e3 *= inv;
  for (int c = lane; c < DDIM; c += 64) {
    cout[c] = e0 * xr0[c] + e1 * xr0[c + DDIM] + e2 * xr0[c + 32 * DDIM] + e3 * xr0[c + 33 * DDIM];
  }
}

// ---------------------------------------------------------------------------
// Kernel 2: CPB relative position bias -> bias [H][N][KC]  (batch independent)
//   one thread per (n,k) pair; idx = n*KC + k
// ---------------------------------------------------------------------------
__global__ __launch_bounds__(256) void cpb_bias_kernel(const float* __restrict__ feats,
                                                       const float* __restrict__ mask,
                                                       const float* __restrict__ w1,
                                                       const float* __restrict__ b1,
                                                       const float* __restrict__ w2,
                                                       const float* __restrict__ b2,
                                                       float* __restrict__ bias) {
  const int idx = blockIdx.x * 256 + threadIdx.x;
  if (idx >= NN * KC) return;
  const float2 f = *(const float2*)&feats[2 * (size_t)idx];
  const float mk = mask[idx];
  float hb[CPBH];
#pragma unroll
  for (int j = 0; j < CPBH; j++) {
    const float tv = fmaf(w1[2 * j], f.x, fmaf(w1[2 * j + 1], f.y, b1[j]));
    hb[j] = 0.5f * tv * (1.0f + erff(tv * 0.70710678118654752f));  // exact gelu
  }
#pragma unroll
  for (int h = 0; h < HH; h++) {
    float acc = b2[h];
#pragma unroll
    for (int j = 0; j < CPBH; j++) acc = fmaf(hb[j], w2[h * CPBH + j], acc);
    bias[(size_t)h * NN * KC + idx] = acc * mk;
  }
}

// ---------------------------------------------------------------------------
// Kernel 3: fp32 GEMM  C[M x Nout] = A[M x 768] * W[Nout x 768]^T (+ bias)
//   128x128 tile, BK=16, 256 threads, 8x8 micro-tile (split 4+4 to keep
//   b128 LDS reads 2-way-max on banks). LDS stride 132 (pad +4, 16B aligned).
// ---------------------------------------------------------------------------
template <bool ADD_BIAS>
__global__ __launch_bounds__(256) void gemm_xwt(const float* __restrict__ A,
                                                const float* __restrict__ W,
                                                const float* __restrict__ bv,
                                                float* __restrict__ C,
                                                int M, int Nout) {
  __shared__ float As[16][132];
  __shared__ float Bs[16][132];
  const int tid = threadIdx.x;
  const int m0 = blockIdx.x * 128;
  const int n0 = blockIdx.y * 128;
  const int lr = tid >> 1;           // 0..127 tile row for staging
  const int lk = (tid & 1) * 8;      // 0 or 8
  const int ty = tid >> 4;           // 0..15
  const int tx = tid & 15;           // 0..15
  float acc[8][8];
#pragma unroll
  for (int i = 0; i < 8; i++)
#pragma unroll
    for (int j = 0; j < 8; j++) acc[i][j] = 0.0f;

  const bool aval = (m0 + lr) < M;
  const float* Ap = A + (size_t)(m0 + lr) * DDIM + lk;
  const float* Wp = W + (size_t)(n0 + lr) * DDIM + lk;

  for (int k0 = 0; k0 < DDIM; k0 += 16) {
    float4 a0 = make_float4(0, 0, 0, 0), a1 = make_float4(0, 0, 0, 0);
    if (aval) {
      a0 = *(const float4*)(Ap + k0);
      a1 = *(const float4*)(Ap + k0 + 4);
    }
    const float4 b0 = *(const float4*)(Wp + k0);
    const float4 b1 = *(const float4*)(Wp + k0 + 4);
    __syncthreads();
    As[lk + 0][lr] = a0.x; As[lk + 1][lr] = a0.y; As[lk + 2][lr] = a0.z; As[lk + 3][lr] = a0.w;
    As[lk + 4][lr] = a1.x; As[lk + 5][lr] = a1.y; As[lk + 6][lr] = a1.z; As[lk + 7][lr] = a1.w;
    Bs[lk + 0][lr] = b0.x; Bs[lk + 1][lr] = b0.y; Bs[lk + 2][lr] = b0.z; Bs[lk + 3][lr] = b0.w;
    Bs[lk + 4][lr] = b1.x; Bs[lk + 5][lr] = b1.y; Bs[lk + 6][lr] = b1.z; Bs[lk + 7][lr] = b1.w;
    __syncthreads();
#pragma unroll
    for (int kkk = 0; kkk < 16; kkk++) {
      float av[8], bw[8];
      *(float4*)&av[0] = *(const float4*)&As[kkk][ty * 4];
      *(float4*)&av[4] = *(const float4*)&As[kkk][64 + ty * 4];
      *(float4*)&bw[0] = *(const float4*)&Bs[kkk][tx * 4];
      *(float4*)&bw[4] = *(const float4*)&Bs[kkk][64 + tx * 4];
#pragma unroll
      for (int i = 0; i < 8; i++)
#pragma unroll
        for (int j = 0; j < 8; j++) acc[i][j] = fmaf(av[i], bw[j], acc[i][j]);
    }
  }
  float4 bb0 = make_float4(0, 0, 0, 0), bb1 = make_float4(0, 0, 0, 0);
  if (ADD_BIAS) {
    bb0 = *(const float4*)&bv[n0 + tx * 4];
    bb1 = *(const float4*)&bv[n0 + 64 + tx * 4];
  }
#pragma unroll
  for (int ig = 0; ig < 2; ig++) {
#pragma unroll
    for (int i = 0; i < 4; i++) {
      const int m = m0 + ig * 64 + ty * 4 + i;
      if (m < M) {
        float* crow = C + (size_t)m * Nout + n0;
        const int r = ig * 4 + i;
        const float4 o0 = make_float4(acc[r][0] + bb0.x, acc[r][1] + bb0.y,
                                      acc[r][2] + bb0.z, acc[r][3] + bb0.w);
        const float4 o1 = make_float4(acc[r][4] + bb1.x, acc[r][5] + bb1.y,
                                      acc[r][6] + bb1.z, acc[r][7] + bb1.w);
        *(float4*)(crow + tx * 4) = o0;
        *(float4*)(crow + 64 + tx * 4) = o1;
      }
    }
  }
}

// ---------------------------------------------------------------------------
// Kernel 4: SDPA with additive bias.
//   grid (33 ntiles, H, B), 128 threads. 32 q-rows per block.
//   K staged transposed in LDS per 64-chunk (b128 reads); logits in LDS;
//   softmax 4 threads/row; AV reads V direct from global (L2-resident).
//   o aliases q (q slice fully consumed before o store).
// ---------------------------------------------------------------------------
__device__ __forceinline__ float f4get(const float4& v, int j) {
  return j == 0 ? v.x : j == 1 ? v.y : j == 2 ? v.z : v.w;
}

__global__ __launch_bounds__(128) void attn_kernel(const float* q,
                                                   const float* __restrict__ kv,
                                                   const float* __restrict__ biasb,
                                                   float* o) {
  __shared__ float qsT[64][36];   // [dd][n]
  __shared__ float ksT[64][68];   // [dd][kcl]
  __shared__ float L[32][268];    // logits / probs
  const int tid = threadIdx.x;
  const int nt = blockIdx.x;
  const int h = blockIdx.y;
  const int b = blockIdx.z;
  const int n0 = nt * 32;

  // ---- stage q transposed ----
  {
    const int n = tid >> 2;              // 0..31
    const int ddb = (tid & 3) * 16;
    const bool val = (n0 + n) < NN;
    const float* qp = q + ((size_t)b * NN + (n0 + n)) * DDIM + h * DH + ddb;
#pragma unroll
    for (int c2 = 0; c2 < 4; c2++) {
      const float4 v = val ? *(const float4*)(qp + 4 * c2) : make_float4(0, 0, 0, 0);
      qsT[ddb + 4 * c2 + 0][n] = v.x;
      qsT[ddb + 4 * c2 + 1][n] = v.y;
      qsT[ddb + 4 * c2 + 2][n] = v.z;
      qsT[ddb + 4 * c2 + 3][n] = v.w;
    }
  }

  const int nq = tid >> 4;  // 0..7  (4 q-rows each)
  const int kq = tid & 15;  // 0..15 (4 k-cols each)
  for (int c = 0; c < 5; c++) {
    const int kctx0 = c * 64;
    __syncthreads();  // prev chunk compute done (and q staging for c==0)
    {
      const int kcl = tid >> 1;          // 0..63
      const int ddb = (tid & 1) * 32;
      const int kctx = kctx0 + kcl;
      const bool val = kctx < KC;
      const float* kp = kv + ((size_t)b * KC + kctx) * (2 * DDIM) + h * DH + ddb;
#pragma unroll
      for (int c2 = 0; c2 < 8; c2++) {
        const float4 v = val ? *(const float4*)(kp + 4 * c2) : make_float4(0, 0, 0, 0);
        ksT[ddb + 4 * c2 + 0][kcl] = v.x;
        ksT[ddb + 4 * c2 + 1][kcl] = v.y;
        ksT[ddb + 4 * c2 + 2][kcl] = v.z;
        ksT[ddb + 4 * c2 + 3][kcl] = v.w;
      }
    }
    __syncthreads();
    float acc[4][4];
#pragma unroll
    for (int i = 0; i < 4; i++)
#pragma unroll
      for (int j = 0; j < 4; j++) acc[i][j] = 0.0f;
#pragma unroll 8
    for (int kkk = 0; kkk < 64; kkk++) {
      float av[4], bw[4];
      *(float4*)&av[0] = *(const float4*)&qsT[kkk][nq * 4];
      *(float4*)&bw[0] = *(const float4*)&ksT[kkk][kq * 4];
#pragma unroll
      for (int i = 0; i < 4; i++)
#pragma unroll
        for (int j = 0; j < 4; j++) acc[i][j] = fmaf(av[i], bw[j], acc[i][j]);
    }
    if (kctx0 + kq * 4 + 3 < 268) {
#pragma unroll
      for (int i = 0; i < 4; i++)
        *(float4*)&L[nq * 4 + i][kctx0 + kq * 4] =
            make_float4(acc[i][0], acc[i][1], acc[i][2], acc[i][3]);
    }
  }
  __syncthreads();

  // ---- softmax (scale + bias, 4 threads per row) ----
  {
    const int row = tid >> 2;
    const int s = tid & 3;
    const int n = n0 + row;
    const bool rowval = n < NN;
    const float* bp = biasb + ((size_t)h * NN + n) * KC;
    float mx = -3.0e38f;
    for (int kc = s; kc < 268; kc += 4) {
      float l = L[row][kc];
      if (rowval && kc < KC) l = fmaf(l, 0.125f, bp[kc]);
      else l = -1.0e30f;
      L[row][kc] = l;
      mx = fmaxf(mx, l);
    }
    mx = fmaxf(mx, __shfl_xor(mx, 1));
    mx = fmaxf(mx, __shfl_xor(mx, 2));
    float sum = 0.0f;
    for (int kc = s; kc < 268; kc += 4) {
      const float p = __expf(L[row][kc] - mx);
      L[row][kc] = p;
      sum += p;
    }
    sum += __shfl_xor(sum, 1);
    sum += __shfl_xor(sum, 2);
    const float inv = 1.0f / sum;
    for (int kc = s; kc < 268; kc += 4) L[row][kc] *= inv;
  }
  __syncthreads();

  // ---- AV: o[n, dd] = sum_k p[n,k] * v[k,dd];  V direct from global (L2) ----
  {
    const int dq = tid & 15;
    const int nq2 = tid >> 4;
    const float* vbase = kv + (size_t)b * KC * (2 * DDIM) + DDIM + h * DH + dq * 4;
    float4 accs[4];
#pragma unroll
    for (int i = 0; i < 4; i++) accs[i] = make_float4(0, 0, 0, 0);
#pragma unroll 2
    for (int kc4 = 0; kc4 < 256; kc4 += 4) {
      float4 pr[4];
#pragma unroll
      for (int i = 0; i < 4; i++) pr[i] = *(const float4*)&L[nq2 * 4 + i][kc4];
#pragma unroll
      for (int j = 0; j < 4; j++) {
        const float4 v4 = *(const float4*)(vbase + (size_t)(kc4 + j) * (2 * DDIM));
#pragma unroll
        for (int i = 0; i < 4; i++) {
          const float w = f4get(pr[i], j);
          accs[i].x = fmaf(w, v4.x, accs[i].x);
          accs[i].y = fmaf(w, v4.y, accs[i].y);
          accs[i].z = fmaf(w, v4.z, accs[i].z);
          accs[i].w = fmaf(w, v4.w, accs[i].w);
        }
      }
    }
    {  // tail k = 256
      const float4 v4 = *(const float4*)(vbase + (size_t)256 * (2 * DDIM));
#pragma unroll
      for (int i = 0; i < 4; i++) {
        const float w = L[nq2 * 4 + i][256];
        accs[i].x = fmaf(w, v4.x, accs[i].x);
        accs[i].y = fmaf(w, v4.y, accs[i].y);
        accs[i].z = fmaf(w, v4.z, accs[i].z);
        accs[i].w = fmaf(w, v4.w, accs[i].w);
      }
    }
#pragma unroll
    for (int i = 0; i < 4; i++) {
      const int n = n0 + nq2 * 4 + i;
      if (n < NN)
        *(float4*)(o + ((size_t)b * NN + n) * DDIM + h * DH + dq * 4) = accs[i];
    }
  }
}

// ---------------------------------------------------------------------------
extern "C" void kernel_launch(void* const* d_in, const int* in_sizes, int n_in,
                              void* d_out, int out_size, void* d_ws, size_t ws_size,
                              hipStream_t stream) {
  (void)in_sizes; (void)n_in; (void)out_size; (void)ws_size;
  const float* x    = (const float*)d_in[0];
  const float* wlog = (const float*)d_in[1];
  const float* Wq   = (const float*)d_in[2];
  const float* Wkv  = (const float*)d_in[3];
  const float* Wo   = (const float*)d_in[4];
  const float* bo   = (const float*)d_in[5];
  const float* w1   = (const float*)d_in[6];
  const float* b1   = (const float*)d_in[7];
  const float* w2   = (const float*)d_in[8];
  const float* b2   = (const float*)d_in[9];
  const float* feats = (const float*)d_in[10];
  const float* mask  = (const float*)d_in[11];
  float* out = (float*)d_out;

  float* ws = (float*)d_ws;
  float* ctx  = ws;                                  // [B, KC, D]        25.3 MB
  float* q    = ctx + (size_t)BB * KC * DDIM;        // [B, N, D] (also o) 100.8 MB
  float* kvb  = q + (size_t)BB * NN * DDIM;          // [B, KC, 2D]       50.5 MB
  float* bias = kvb + (size_t)BB * KC * 2 * DDIM;    // [H, N, KC]        12.6 MB

  // 1) pooling -> ctx
  pool_ctx_kernel<<<dim3(BB * KC), dim3(64), 0, stream>>>(x, wlog, ctx);
  // 2) CPB bias (batch independent)
  cpb_bias_kernel<<<dim3((NN * KC + 255) / 256), dim3(256), 0, stream>>>(
      feats, mask, w1, b1, w2, b2, bias);
  // 3) q = x @ Wq^T   [32800 x 768]
  gemm_xwt<false><<<dim3((BB * NN + 127) / 128, DDIM / 128), dim3(256), 0, stream>>>(
      x, Wq, nullptr, q, BB * NN, DDIM);
  // 4) kv = ctx @ Wkv^T  [8224 x 1536]
  gemm_xwt<false><<<dim3((BB * KC + 127) / 128, (2 * DDIM) / 128), dim3(256), 0, stream>>>(
      ctx, Wkv, nullptr, kvb, BB * KC, 2 * DDIM);
  // 5) attention (o overwrites q in place)
  attn_kernel<<<dim3(33, HH, BB), dim3(128), 0, stream>>>(q, kvb, bias, q);
  // 6) out = o @ Wo^T + bo
  gemm_xwt<true><<<dim3((BB * NN + 127) / 128, DDIM / 128), dim3(256), 0, stream>>>(
      q, Wo, bo, out, BB * NN, DDIM);
}

// Round 2
// 1214.085 us; speedup vs baseline: 2.3273x; 2.3273x over previous
//
#include <hip/hip_runtime.h>
#include <math.h>

#define BB 32
#define NN 1025
#define DDIM 768
#define HH 12
#define DHD 64
#define KC 257
#define CPBH 32

typedef unsigned int u32;
typedef unsigned short u16;
typedef unsigned char u8;
typedef __attribute__((ext_vector_type(8))) short s8v;
typedef __attribute__((ext_vector_type(4))) float f4v;

__device__ __forceinline__ u16 f2bf(float f) {
  union { float f; u32 u; } v; v.f = f;
  return (u16)((v.u + 0x7fffu + ((v.u >> 16) & 1u)) >> 16);
}
__device__ __forceinline__ float bf2f(u16 h) {
  union { u32 u; float f; } v; v.u = ((u32)h) << 16;
  return v.f;
}
// async global->LDS, 16B per lane; LDS dest = wave-uniform base + lane*16
__device__ __forceinline__ void gload16(const u16* g, u16* l) {
  __builtin_amdgcn_global_load_lds((const __attribute__((address_space(1))) void*)g,
                                   (__attribute__((address_space(3))) void*)l, 16, 0, 0);
}

// ---------------------------------------------------------------------------
// fp32 -> bf16 cast (8 elements/thread)
// ---------------------------------------------------------------------------
__global__ __launch_bounds__(256) void cast_bf16_kernel(const float* __restrict__ s,
                                                        u16* __restrict__ d, int n8) {
  const int i = blockIdx.x * 256 + threadIdx.x;
  if (i >= n8) return;
  const float4 f0 = ((const float4*)s)[2 * i];
  const float4 f1 = ((const float4*)s)[2 * i + 1];
  s8v o;
  o[0] = (short)f2bf(f0.x); o[1] = (short)f2bf(f0.y);
  o[2] = (short)f2bf(f0.z); o[3] = (short)f2bf(f0.w);
  o[4] = (short)f2bf(f1.x); o[5] = (short)f2bf(f1.y);
  o[6] = (short)f2bf(f1.z); o[7] = (short)f2bf(f1.w);
  *(s8v*)&d[8 * (size_t)i] = o;
}

// fp32 -> (bf16 hi, bf16 lo) split cast
__global__ __launch_bounds__(256) void split_bf16_kernel(const float* __restrict__ s,
                                                         u16* __restrict__ dh,
                                                         u16* __restrict__ dl, int n8) {
  const int i = blockIdx.x * 256 + threadIdx.x;
  if (i >= n8) return;
  s8v oh, ol;
#pragma unroll
  for (int j = 0; j < 8; j++) {
    const float f = s[8 * (size_t)i + j];
    const u16 hb = f2bf(f);
    oh[j] = (short)hb;
    ol[j] = (short)f2bf(f - bf2f(hb));
  }
  *(s8v*)&dh[8 * (size_t)i] = oh;
  *(s8v*)&dl[8 * (size_t)i] = ol;
}

// ---------------------------------------------------------------------------
// tiled softmax pooling -> ctx [B, KC, D] (bf16 out)
// ---------------------------------------------------------------------------
__global__ __launch_bounds__(64) void pool_ctx_kernel(const float* __restrict__ x,
                                                      const float* __restrict__ wlog,
                                                      u16* __restrict__ ctx) {
  const int bid = blockIdx.x;
  const int b = bid / KC;
  const int kk = bid % KC;
  const int lane = threadIdx.x;
  const float* xb = x + (size_t)b * NN * DDIM;
  u16* cout = ctx + ((size_t)b * KC + kk) * DDIM;
  if (kk == 0) {
    for (int c = lane; c < DDIM; c += 64) cout[c] = f2bf(xb[c]);
    return;
  }
  const int t = kk - 1;
  const int gy = t >> 4, gx = t & 15;
  const int r0 = 1 + gy * 64 + gx * 2;
  const float* xr0 = xb + (size_t)r0 * DDIM;
  float s0 = 0.f, s1 = 0.f, s2 = 0.f, s3 = 0.f;
  for (int c = lane; c < DDIM; c += 64) {
    const float w = wlog[c];
    s0 = fmaf(xr0[c], w, s0);
    s1 = fmaf(xr0[c + DDIM], w, s1);
    s2 = fmaf(xr0[c + 32 * DDIM], w, s2);
    s3 = fmaf(xr0[c + 33 * DDIM], w, s3);
  }
#pragma unroll
  for (int off = 32; off; off >>= 1) {
    s0 += __shfl_xor(s0, off);
    s1 += __shfl_xor(s1, off);
    s2 += __shfl_xor(s2, off);
    s3 += __shfl_xor(s3, off);
  }
  const float m = fmaxf(fmaxf(s0, s1), fmaxf(s2, s3));
  float e0 = expf(s0 - m), e1 = expf(s1 - m), e2 = expf(s2 - m), e3 = expf(s3 - m);
  const float inv = 1.0f / (e0 + e1 + e2 + e3);
  e0 *= inv; e1 *= inv; e2 *= inv; e3 *= inv;
  for (int c = lane; c < DDIM; c += 64) {
    cout[c] = f2bf(e0 * xr0[c] + e1 * xr0[c + DDIM] + e2 * xr0[c + 32 * DDIM] +
                   e3 * xr0[c + 33 * DDIM]);
  }
}

// ---------------------------------------------------------------------------
// CPB relative position bias -> bias [H][N][KC] fp32
// ---------------------------------------------------------------------------
__global__ __launch_bounds__(256) void cpb_bias_kernel(const float* __restrict__ feats,
                                                       const float* __restrict__ mask,
                                                       const float* __restrict__ w1,
                                                       const float* __restrict__ b1,
                                                       const float* __restrict__ w2,
                                                       const float* __restrict__ b2,
                                                       float* __restrict__ bias) {
  const int idx = blockIdx.x * 256 + threadIdx.x;
  if (idx >= NN * KC) return;
  const float2 f = *(const float2*)&feats[2 * (size_t)idx];
  const float mk = mask[idx];
  float hb[CPBH];
#pragma unroll
  for (int j = 0; j < CPBH; j++) {
    const float tv = fmaf(w1[2 * j], f.x, fmaf(w1[2 * j + 1], f.y, b1[j]));
    hb[j] = 0.5f * tv * (1.0f + erff(tv * 0.70710678118654752f));
  }
#pragma unroll
  for (int h = 0; h < HH; h++) {
    float acc = b2[h];
#pragma unroll
    for (int j = 0; j < CPBH; j++) acc = fmaf(hb[j], w2[h * CPBH + j], acc);
    bias[(size_t)h * NN * KC + idx] = acc * mk;
  }
}

// ---------------------------------------------------------------------------
// bf16 MFMA GEMM: C[M x Nout] = A[M x 768] * W[Nout x 768]^T (+ bias)
//   m97 structure: 128xBN tile, BK=32, global_load_lds width 16, 2-barrier.
//   SPLIT: A = Ah+Al, B = Bh+Bl, 3 products (near-fp32 accuracy), BN=64.
// ---------------------------------------------------------------------------
template <int SPLIT, int WRITE_BF16, int ADD_BIAS>
__global__ __launch_bounds__(256) void gemm_mfma(const u16* __restrict__ Ah,
                                                 const u16* __restrict__ Al,
                                                 const u16* __restrict__ Bh,
                                                 const u16* __restrict__ Bl,
                                                 const float* __restrict__ bias,
                                                 float* __restrict__ Cf,
                                                 u16* __restrict__ Cb, int M, int Nout) {
  constexpr int BN = SPLIT ? 64 : 128;
  constexpr int NTI = SPLIT ? 2 : 4;
  __shared__ u16 AhL[128 * 32];
  __shared__ u16 BhL[BN * 32];
  __shared__ u16 AlL[SPLIT ? 128 * 32 : 8];
  __shared__ u16 BlL[SPLIT ? BN * 32 : 8];
  const int tid = threadIdx.x;
  const int w = tid >> 6, l = tid & 63;
  const int lane16 = l & 15, quad = l >> 4;
  const int m0 = blockIdx.x * 128, n0 = blockIdx.y * BN;
  const int sr = l >> 2, sc = (l & 3) * 8;
  const int ar0 = min(m0 + w * 32 + sr, M - 1);
  const int ar1 = min(m0 + w * 32 + 16 + sr, M - 1);
  const u16* ap0 = Ah + (size_t)ar0 * DDIM + sc;
  const u16* ap1 = Ah + (size_t)ar1 * DDIM + sc;
  const u16* alp0 = nullptr; const u16* alp1 = nullptr;
  const u16* bp0 = nullptr; const u16* bp1 = nullptr; const u16* blp0 = nullptr;
  if constexpr (SPLIT) {
    alp0 = Al + (size_t)ar0 * DDIM + sc;
    alp1 = Al + (size_t)ar1 * DDIM + sc;
    bp0 = Bh + (size_t)(n0 + w * 16 + sr) * DDIM + sc;
    blp0 = Bl + (size_t)(n0 + w * 16 + sr) * DDIM + sc;
  } else {
    bp0 = Bh + (size_t)(n0 + w * 32 + sr) * DDIM + sc;
    bp1 = Bh + (size_t)(n0 + w * 32 + 16 + sr) * DDIM + sc;
  }
  f4v acc[4][NTI];
#pragma unroll
  for (int mt = 0; mt < 4; mt++)
#pragma unroll
    for (int nt = 0; nt < NTI; nt++) acc[mt][nt] = (f4v){0.f, 0.f, 0.f, 0.f};
  const int mh = (w & 1) * 64;
  const int nh = (w >> 1) * (SPLIT ? 32 : 64);

  for (int k0 = 0; k0 < DDIM; k0 += 32) {
    __syncthreads();
    gload16(ap0 + k0, &AhL[(w * 32) * 32]);
    gload16(ap1 + k0, &AhL[(w * 32 + 16) * 32]);
    if constexpr (SPLIT) {
      gload16(alp0 + k0, &AlL[(w * 32) * 32]);
      gload16(alp1 + k0, &AlL[(w * 32 + 16) * 32]);
      gload16(bp0 + k0, &BhL[(w * 16) * 32]);
      gload16(blp0 + k0, &BlL[(w * 16) * 32]);
    } else {
      gload16(bp0 + k0, &BhL[(w * 32) * 32]);
      gload16(bp1 + k0, &BhL[(w * 32 + 16) * 32]);
    }
    __syncthreads();
    s8v af[4], afl[4];
#pragma unroll
    for (int mt = 0; mt < 4; mt++) {
      af[mt] = *(const s8v*)&AhL[(mh + mt * 16 + lane16) * 32 + quad * 8];
      if constexpr (SPLIT)
        afl[mt] = *(const s8v*)&AlL[(mh + mt * 16 + lane16) * 32 + quad * 8];
    }
#pragma unroll
    for (int nt = 0; nt < NTI; nt++) {
      const s8v bfh = *(const s8v*)&BhL[(nh + nt * 16 + lane16) * 32 + quad * 8];
      s8v bfl;
      if constexpr (SPLIT)
        bfl = *(const s8v*)&BlL[(nh + nt * 16 + lane16) * 32 + quad * 8];
#pragma unroll
      for (int mt = 0; mt < 4; mt++) {
        acc[mt][nt] = __builtin_amdgcn_mfma_f32_16x16x32_bf16(af[mt], bfh, acc[mt][nt], 0, 0, 0);
        if constexpr (SPLIT) {
          acc[mt][nt] = __builtin_amdgcn_mfma_f32_16x16x32_bf16(afl[mt], bfh, acc[mt][nt], 0, 0, 0);
          acc[mt][nt] = __builtin_amdgcn_mfma_f32_16x16x32_bf16(af[mt], bfl, acc[mt][nt], 0, 0, 0);
        }
      }
    }
  }
#pragma unroll
  for (int mt = 0; mt < 4; mt++)
#pragma unroll
    for (int nt = 0; nt < NTI; nt++)
#pragma unroll
      for (int r = 0; r < 4; r++) {
        const int row = m0 + mh + mt * 16 + quad * 4 + r;
        if (row < M) {
          const int col = n0 + nh + nt * 16 + lane16;
          float v = acc[mt][nt][r];
          if (ADD_BIAS) v += bias[col];
          if (WRITE_BF16) Cb[(size_t)row * Nout + col] = f2bf(v);
          else Cf[(size_t)row * Nout + col] = v;
        }
      }
}

// ---------------------------------------------------------------------------
// MFMA attention. Block: 256 thr (4 waves), grid (17 qtiles, H, B).
//   Wave w owns q rows qt*64 + w*16 .. +15. S=QK^T via mfma (frags direct
//   from global), register softmax (+bias, mask), P->LDS bf16 (chunked),
//   PV vs LDS-transposed V. Writes o split (hi/lo bf16) for the out-GEMM.
//   Strides: Vt 328, P 72 -> hot ds_read_b128 conflict-free.
// ---------------------------------------------------------------------------
#define VTS 328
#define PLS 72

__global__ __launch_bounds__(256) void attn_mfma(const u16* qb,
                                                 const u16* __restrict__ kvb,
                                                 const float* __restrict__ biasb,
                                                 u16* oh, u16* __restrict__ ol) {
  __shared__ u16 VtL[64 * VTS];       // Vt[c][k], k padded to 320
  __shared__ u16 PL[4][16 * PLS];     // per-wave P chunk [16][64]
  const int tid = threadIdx.x;
  const int w = tid >> 6, l = tid & 63;
  const int lane16 = l & 15, quad = l >> 4;
  const int h = blockIdx.y, b = blockIdx.z;
  const int n_base = blockIdx.x * 64 + w * 16;

  // stage V transposed (bf16 copy from kv)
  for (int i = tid; i < 64 * 320; i += 256) {
    const int k = i >> 6, c = i & 63;
    u16 v = 0;
    if (k < KC) v = kvb[((size_t)b * KC + k) * (2 * DDIM) + DDIM + h * DHD + c];
    VtL[c * VTS + k] = v;
  }

  // q fragments (reused across all 17 k-tiles)
  const int qrow = min(n_base + lane16, NN - 1);
  const u16* qp = qb + ((size_t)b * NN + qrow) * DDIM + h * DHD + quad * 8;
  const s8v qf0 = *(const s8v*)qp;
  const s8v qf1 = *(const s8v*)(qp + 32);

  // S = Q K^T  (17 tiles of 16 cols)
  f4v S[17];
#pragma unroll
  for (int t = 0; t < 17; t++) {
    const int krow = min(t * 16 + lane16, KC - 1);
    const u16* kp = kvb + ((size_t)b * KC + krow) * (2 * DDIM) + h * DHD + quad * 8;
    const s8v kf0 = *(const s8v*)kp;
    const s8v kf1 = *(const s8v*)(kp + 32);
    f4v z = {0.f, 0.f, 0.f, 0.f};
    z = __builtin_amdgcn_mfma_f32_16x16x32_bf16(qf0, kf0, z, 0, 0, 0);
    z = __builtin_amdgcn_mfma_f32_16x16x32_bf16(qf1, kf1, z, 0, 0, 0);
    S[t] = z;
  }

  // scale + bias + mask; register softmax across 16-lane groups
  float mx[4] = {-1e30f, -1e30f, -1e30f, -1e30f};
#pragma unroll
  for (int t = 0; t < 17; t++) {
    const int cc = t * 16 + lane16;
#pragma unroll
    for (int r = 0; r < 4; r++) {
      const int row = n_base + quad * 4 + r;
      float v = -1e30f;
      if (cc < KC && row < NN)
        v = fmaf(S[t][r], 0.125f, biasb[((size_t)h * NN + row) * KC + cc]);
      S[t][r] = v;
      mx[r] = fmaxf(mx[r], v);
    }
  }
#pragma unroll
  for (int r = 0; r < 4; r++) {
    mx[r] = fmaxf(mx[r], __shfl_xor(mx[r], 1));
    mx[r] = fmaxf(mx[r], __shfl_xor(mx[r], 2));
    mx[r] = fmaxf(mx[r], __shfl_xor(mx[r], 4));
    mx[r] = fmaxf(mx[r], __shfl_xor(mx[r], 8));
  }
  float sm[4] = {0.f, 0.f, 0.f, 0.f};
#pragma unroll
  for (int t = 0; t < 17; t++)
#pragma unroll
    for (int r = 0; r < 4; r++) {
      const float p = __expf(S[t][r] - mx[r]);
      S[t][r] = p;
      sm[r] += p;
    }
#pragma unroll
  for (int r = 0; r < 4; r++) {
    sm[r] += __shfl_xor(sm[r], 1);
    sm[r] += __shfl_xor(sm[r], 2);
    sm[r] += __shfl_xor(sm[r], 4);
    sm[r] += __shfl_xor(sm[r], 8);
    sm[r] = 1.0f / sm[r];
  }

  f4v O[4];
#pragma unroll
  for (int nt = 0; nt < 4; nt++) O[nt] = (f4v){0.f, 0.f, 0.f, 0.f};

  __syncthreads();  // Vt staged

  u16* PLw = PL[w];
#pragma unroll
  for (int ch = 0; ch < 5; ch++) {
    // write P chunk (C-layout -> LDS), zeros beyond col 271
#pragma unroll
    for (int tt = 0; tt < 4; tt++) {
      const int t = ch * 4 + tt;
#pragma unroll
      for (int r = 0; r < 4; r++) {
        float pv = 0.f;
        if (t < 17) pv = S[t][r] * sm[r];
        PLw[(quad * 4 + r) * PLS + tt * 16 + lane16] = f2bf(pv);
      }
    }
    __syncthreads();
#pragma unroll
    for (int ks = 0; ks < 2; ks++) {
      const s8v a = *(const s8v*)&PLw[lane16 * PLS + ks * 32 + quad * 8];
#pragma unroll
      for (int nt = 0; nt < 4; nt++) {
        const s8v bfr =
            *(const s8v*)&VtL[(nt * 16 + lane16) * VTS + ch * 64 + ks * 32 + quad * 8];
        O[nt] = __builtin_amdgcn_mfma_f32_16x16x32_bf16(a, bfr, O[nt], 0, 0, 0);
      }
    }
    __syncthreads();
  }

  // epilogue: split-store o (hi/lo bf16)
#pragma unroll
  for (int nt = 0; nt < 4; nt++)
#pragma unroll
    for (int r = 0; r < 4; r++) {
      const int n = n_base + quad * 4 + r;
      if (n < NN) {
        const size_t idx = ((size_t)b * NN + n) * DDIM + h * DHD + nt * 16 + lane16;
        const float v = O[nt][r];
        const u16 hb = f2bf(v);
        oh[idx] = hb;
        ol[idx] = f2bf(v - bf2f(hb));
      }
    }
}

// ---------------------------------------------------------------------------
extern "C" void kernel_launch(void* const* d_in, const int* in_sizes, int n_in,
                              void* d_out, int out_size, void* d_ws, size_t ws_size,
                              hipStream_t stream) {
  (void)in_sizes; (void)n_in; (void)out_size; (void)ws_size;
  const float* x    = (const float*)d_in[0];
  const float* wlog = (const float*)d_in[1];
  const float* Wq   = (const float*)d_in[2];
  const float* Wkv  = (const float*)d_in[3];
  const float* Wo   = (const float*)d_in[4];
  const float* bo   = (const float*)d_in[5];
  const float* w1   = (const float*)d_in[6];
  const float* b1   = (const float*)d_in[7];
  const float* w2   = (const float*)d_in[8];
  const float* b2   = (const float*)d_in[9];
  const float* feats = (const float*)d_in[10];
  const float* mask  = (const float*)d_in[11];
  float* out = (float*)d_out;

  u8* p = (u8*)d_ws;
  u16* xb    = (u16*)(p + 0);            // 50,380,800 B  (also ol after q-gemm)
  u16* ctxb  = (u16*)(p + 50380800);     // 12,632,064
  u16* Wqb   = (u16*)(p + 63012864);     //  1,179,648
  u16* Wkvb  = (u16*)(p + 64192512);     //  2,359,296
  u16* Woh   = (u16*)(p + 66551808);     //  1,179,648
  u16* Wol   = (u16*)(p + 67731456);     //  1,179,648
  u16* qb    = (u16*)(p + 68911104);     // 50,380,800  (also o_hi)
  u16* kvb   = (u16*)(p + 119291904);    // 25,264,128
  float* bias = (float*)(p + 144556032); // 12,645,900  -> total ~157.2 MB

  const int nx8 = (BB * NN * DDIM) / 8;        // 3,148,800
  cast_bf16_kernel<<<dim3((nx8 + 255) / 256), dim3(256), 0, stream>>>(x, xb, nx8);
  cast_bf16_kernel<<<dim3(288), dim3(256), 0, stream>>>(Wq, Wqb, (DDIM * DDIM) / 8);
  cast_bf16_kernel<<<dim3(576), dim3(256), 0, stream>>>(Wkv, Wkvb, (2 * DDIM * DDIM) / 8);
  split_bf16_kernel<<<dim3(288), dim3(256), 0, stream>>>(Wo, Woh, Wol, (DDIM * DDIM) / 8);
  pool_ctx_kernel<<<dim3(BB * KC), dim3(64), 0, stream>>>(x, wlog, ctxb);
  cpb_bias_kernel<<<dim3((NN * KC + 255) / 256), dim3(256), 0, stream>>>(
      feats, mask, w1, b1, w2, b2, bias);
  // q = x @ Wq^T (bf16 out)
  gemm_mfma<0, 1, 0><<<dim3(257, 6), dim3(256), 0, stream>>>(
      xb, nullptr, Wqb, nullptr, nullptr, nullptr, qb, BB * NN, DDIM);
  // kv = ctx @ Wkv^T (bf16 out)
  gemm_mfma<0, 1, 0><<<dim3(65, 12), dim3(256), 0, stream>>>(
      ctxb, nullptr, Wkvb, nullptr, nullptr, nullptr, kvb, BB * KC, 2 * DDIM);
  // attention: o_hi -> qb (safe self-alias), o_lo -> xb (dead)
  attn_mfma<<<dim3(17, HH, BB), dim3(256), 0, stream>>>(qb, kvb, bias, qb, xb);
  // out = (oh+ol) @ (Woh+Wol)^T + bo, split 3-product for accuracy
  gemm_mfma<1, 0, 1><<<dim3(257, 12), dim3(256), 0, stream>>>(
      qb, xb, Woh, Wol, bo, out, nullptr, BB * NN, DDIM);
}

// Round 3
// 777.264 us; speedup vs baseline: 3.6352x; 1.5620x over previous
//
#include <hip/hip_runtime.h>
#include <math.h>

#define BB 32
#define NN 1025
#define DDIM 768
#define HH 12
#define DHD 64
#define KC 257
#define CPBH 32

#define BT_K 320
#define BT_N 1088
#define SCALE_LOG2E 0.18033688011112042f  /* 0.125 * log2(e) */

typedef unsigned int u32;
typedef unsigned short u16;
typedef unsigned char u8;
typedef __attribute__((ext_vector_type(8))) short s8v;
typedef __attribute__((ext_vector_type(4))) float f4v;

__device__ __forceinline__ u16 f2bf(float f) {
  union { float f; u32 u; } v; v.f = f;
  return (u16)((v.u + 0x7fffu + ((v.u >> 16) & 1u)) >> 16);
}
__device__ __forceinline__ float bf2f(u16 h) {
  union { u32 u; float f; } v; v.u = ((u32)h) << 16;
  return v.f;
}
__device__ __forceinline__ void gload16(const u16* g, u16* l) {
  __builtin_amdgcn_global_load_lds((const __attribute__((address_space(1))) void*)g,
                                   (__attribute__((address_space(3))) void*)l, 16, 0, 0);
}

// ---------------------------------------------------------------------------
// fp32 -> bf16 cast (8 elements/thread)
// ---------------------------------------------------------------------------
__global__ __launch_bounds__(256) void cast_bf16_kernel(const float* __restrict__ s,
                                                        u16* __restrict__ d, int n8) {
  const int i = blockIdx.x * 256 + threadIdx.x;
  if (i >= n8) return;
  const float4 f0 = ((const float4*)s)[2 * i];
  const float4 f1 = ((const float4*)s)[2 * i + 1];
  s8v o;
  o[0] = (short)f2bf(f0.x); o[1] = (short)f2bf(f0.y);
  o[2] = (short)f2bf(f0.z); o[3] = (short)f2bf(f0.w);
  o[4] = (short)f2bf(f1.x); o[5] = (short)f2bf(f1.y);
  o[6] = (short)f2bf(f1.z); o[7] = (short)f2bf(f1.w);
  *(s8v*)&d[8 * (size_t)i] = o;
}

// fp32 -> (bf16 hi, bf16 lo) split cast
__global__ __launch_bounds__(256) void split_bf16_kernel(const float* __restrict__ s,
                                                         u16* __restrict__ dh,
                                                         u16* __restrict__ dl, int n8) {
  const int i = blockIdx.x * 256 + threadIdx.x;
  if (i >= n8) return;
  s8v oh, ol;
#pragma unroll
  for (int j = 0; j < 8; j++) {
    const float f = s[8 * (size_t)i + j];
    const u16 hb = f2bf(f);
    oh[j] = (short)hb;
    ol[j] = (short)f2bf(f - bf2f(hb));
  }
  *(s8v*)&dh[8 * (size_t)i] = oh;
  *(s8v*)&dl[8 * (size_t)i] = ol;
}

// ---------------------------------------------------------------------------
// tiled softmax pooling -> ctx [B, KC, D] (bf16 out)
// ---------------------------------------------------------------------------
__global__ __launch_bounds__(64) void pool_ctx_kernel(const float* __restrict__ x,
                                                      const float* __restrict__ wlog,
                                                      u16* __restrict__ ctx) {
  const int bid = blockIdx.x;
  const int b = bid / KC;
  const int kk = bid % KC;
  const int lane = threadIdx.x;
  const float* xb = x + (size_t)b * NN * DDIM;
  u16* cout = ctx + ((size_t)b * KC + kk) * DDIM;
  if (kk == 0) {
    for (int c = lane; c < DDIM; c += 64) cout[c] = f2bf(xb[c]);
    return;
  }
  const int t = kk - 1;
  const int gy = t >> 4, gx = t & 15;
  const int r0 = 1 + gy * 64 + gx * 2;
  const float* xr0 = xb + (size_t)r0 * DDIM;
  float s0 = 0.f, s1 = 0.f, s2 = 0.f, s3 = 0.f;
  for (int c = lane; c < DDIM; c += 64) {
    const float w = wlog[c];
    s0 = fmaf(xr0[c], w, s0);
    s1 = fmaf(xr0[c + DDIM], w, s1);
    s2 = fmaf(xr0[c + 32 * DDIM], w, s2);
    s3 = fmaf(xr0[c + 33 * DDIM], w, s3);
  }
#pragma unroll
  for (int off = 32; off; off >>= 1) {
    s0 += __shfl_xor(s0, off);
    s1 += __shfl_xor(s1, off);
    s2 += __shfl_xor(s2, off);
    s3 += __shfl_xor(s3, off);
  }
  const float m = fmaxf(fmaxf(s0, s1), fmaxf(s2, s3));
  float e0 = expf(s0 - m), e1 = expf(s1 - m), e2 = expf(s2 - m), e3 = expf(s3 - m);
  const float inv = 1.0f / (e0 + e1 + e2 + e3);
  e0 *= inv; e1 *= inv; e2 *= inv; e3 *= inv;
  for (int c = lane; c < DDIM; c += 64) {
    cout[c] = f2bf(e0 * xr0[c] + e1 * xr0[c + DDIM] + e2 * xr0[c + 32 * DDIM] +
                   e3 * xr0[c + 33 * DDIM]);
  }
}

// ---------------------------------------------------------------------------
// CPB bias, transposed+padded layout: biasT[h][k=320][n=1088] fp32,
// value = (mlp(feats)+b2)*mask*log2e for valid (k<257,n<1025), else -1e30.
// Thread idx = k*1088 + n -> coalesced stores.
// ---------------------------------------------------------------------------
__global__ __launch_bounds__(256) void cpb_biasT_kernel(const float* __restrict__ feats,
                                                        const float* __restrict__ mask,
                                                        const float* __restrict__ w1,
                                                        const float* __restrict__ b1,
                                                        const float* __restrict__ w2,
                                                        const float* __restrict__ b2,
                                                        float* __restrict__ biasT) {
  const int idx = blockIdx.x * 256 + threadIdx.x;
  if (idx >= BT_K * BT_N) return;
  const int k = idx / BT_N;
  const int n = idx - k * BT_N;
  const bool valid = (k < KC) && (n < NN);
  float out[HH];
  if (valid) {
    const float2 f = *(const float2*)&feats[2 * ((size_t)n * KC + k)];
    const float mk = mask[(size_t)n * KC + k] * 1.4426950408889634f;
    float hb[CPBH];
#pragma unroll
    for (int j = 0; j < CPBH; j++) {
      const float tv = fmaf(w1[2 * j], f.x, fmaf(w1[2 * j + 1], f.y, b1[j]));
      hb[j] = 0.5f * tv * (1.0f + erff(tv * 0.70710678118654752f));
    }
#pragma unroll
    for (int h = 0; h < HH; h++) {
      float acc = b2[h];
#pragma unroll
      for (int j = 0; j < CPBH; j++) acc = fmaf(hb[j], w2[h * CPBH + j], acc);
      out[h] = acc * mk;
    }
  } else {
#pragma unroll
    for (int h = 0; h < HH; h++) out[h] = -1.0e30f;
  }
#pragma unroll
  for (int h = 0; h < HH; h++) biasT[(size_t)h * BT_K * BT_N + idx] = out[h];
}

// ---------------------------------------------------------------------------
// bf16 MFMA GEMM (unchanged from round 2)
// ---------------------------------------------------------------------------
template <int SPLIT, int WRITE_BF16, int ADD_BIAS>
__global__ __launch_bounds__(256) void gemm_mfma(const u16* __restrict__ Ah,
                                                 const u16* __restrict__ Al,
                                                 const u16* __restrict__ Bh,
                                                 const u16* __restrict__ Bl,
                                                 const float* __restrict__ bias,
                                                 float* __restrict__ Cf,
                                                 u16* __restrict__ Cb, int M, int Nout) {
  constexpr int BN = SPLIT ? 64 : 128;
  constexpr int NTI = SPLIT ? 2 : 4;
  __shared__ u16 AhL[128 * 32];
  __shared__ u16 BhL[BN * 32];
  __shared__ u16 AlL[SPLIT ? 128 * 32 : 8];
  __shared__ u16 BlL[SPLIT ? BN * 32 : 8];
  const int tid = threadIdx.x;
  const int w = tid >> 6, l = tid & 63;
  const int lane16 = l & 15, quad = l >> 4;
  const int m0 = blockIdx.x * 128, n0 = blockIdx.y * BN;
  const int sr = l >> 2, sc = (l & 3) * 8;
  const int ar0 = min(m0 + w * 32 + sr, M - 1);
  const int ar1 = min(m0 + w * 32 + 16 + sr, M - 1);
  const u16* ap0 = Ah + (size_t)ar0 * DDIM + sc;
  const u16* ap1 = Ah + (size_t)ar1 * DDIM + sc;
  const u16* alp0 = nullptr; const u16* alp1 = nullptr;
  const u16* bp0 = nullptr; const u16* bp1 = nullptr; const u16* blp0 = nullptr;
  if constexpr (SPLIT) {
    alp0 = Al + (size_t)ar0 * DDIM + sc;
    alp1 = Al + (size_t)ar1 * DDIM + sc;
    bp0 = Bh + (size_t)(n0 + w * 16 + sr) * DDIM + sc;
    blp0 = Bl + (size_t)(n0 + w * 16 + sr) * DDIM + sc;
  } else {
    bp0 = Bh + (size_t)(n0 + w * 32 + sr) * DDIM + sc;
    bp1 = Bh + (size_t)(n0 + w * 32 + 16 + sr) * DDIM + sc;
  }
  f4v acc[4][NTI];
#pragma unroll
  for (int mt = 0; mt < 4; mt++)
#pragma unroll
    for (int nt = 0; nt < NTI; nt++) acc[mt][nt] = (f4v){0.f, 0.f, 0.f, 0.f};
  const int mh = (w & 1) * 64;
  const int nh = (w >> 1) * (SPLIT ? 32 : 64);

  for (int k0 = 0; k0 < DDIM; k0 += 32) {
    __syncthreads();
    gload16(ap0 + k0, &AhL[(w * 32) * 32]);
    gload16(ap1 + k0, &AhL[(w * 32 + 16) * 32]);
    if constexpr (SPLIT) {
      gload16(alp0 + k0, &AlL[(w * 32) * 32]);
      gload16(alp1 + k0, &AlL[(w * 32 + 16) * 32]);
      gload16(bp0 + k0, &BhL[(w * 16) * 32]);
      gload16(blp0 + k0, &BlL[(w * 16) * 32]);
    } else {
      gload16(bp0 + k0, &BhL[(w * 32) * 32]);
      gload16(bp1 + k0, &BhL[(w * 32 + 16) * 32]);
    }
    __syncthreads();
    s8v af[4], afl[4];
#pragma unroll
    for (int mt = 0; mt < 4; mt++) {
      af[mt] = *(const s8v*)&AhL[(mh + mt * 16 + lane16) * 32 + quad * 8];
      if constexpr (SPLIT)
        afl[mt] = *(const s8v*)&AlL[(mh + mt * 16 + lane16) * 32 + quad * 8];
    }
#pragma unroll
    for (int nt = 0; nt < NTI; nt++) {
      const s8v bfh = *(const s8v*)&BhL[(nh + nt * 16 + lane16) * 32 + quad * 8];
      s8v bfl;
      if constexpr (SPLIT)
        bfl = *(const s8v*)&BlL[(nh + nt * 16 + lane16) * 32 + quad * 8];
#pragma unroll
      for (int mt = 0; mt < 4; mt++) {
        acc[mt][nt] = __builtin_amdgcn_mfma_f32_16x16x32_bf16(af[mt], bfh, acc[mt][nt], 0, 0, 0);
        if constexpr (SPLIT) {
          acc[mt][nt] = __builtin_amdgcn_mfma_f32_16x16x32_bf16(afl[mt], bfh, acc[mt][nt], 0, 0, 0);
          acc[mt][nt] = __builtin_amdgcn_mfma_f32_16x16x32_bf16(af[mt], bfl, acc[mt][nt], 0, 0, 0);
        }
      }
    }
  }
#pragma unroll
  for (int mt = 0; mt < 4; mt++)
#pragma unroll
    for (int nt = 0; nt < NTI; nt++)
#pragma unroll
      for (int r = 0; r < 4; r++) {
        const int row = m0 + mh + mt * 16 + quad * 4 + r;
        if (row < M) {
          const int col = n0 + nh + nt * 16 + lane16;
          float v = acc[mt][nt][r];
          if (ADD_BIAS) v += bias[col];
          if (WRITE_BF16) Cb[(size_t)row * Nout + col] = f2bf(v);
          else Cf[(size_t)row * Nout + col] = v;
        }
      }
}

// ---------------------------------------------------------------------------
// V transpose: kvb V-half [b][k][h*64+c] -> vt [b][h][c][k pad 320] bf16,
// zero-filled for k >= 257. Coalesced b128 reads, 16B-run scatter writes.
// ---------------------------------------------------------------------------
__global__ __launch_bounds__(256) void transpose_v_kernel(const u16* __restrict__ kvb,
                                                          u16* __restrict__ vt) {
  const int bh = blockIdx.x;
  const int b = bh / HH, h = bh % HH;
  const int tid = threadIdx.x;
  const int kk = tid >> 3;           // 0..31
  const int c0 = (tid & 7) * 8;      // 0..56
  u16* dbase = vt + (((size_t)b * HH + h) * 64 + c0) * BT_K;
#pragma unroll
  for (int ch = 0; ch < 10; ch++) {
    const int k = ch * 32 + kk;
    s8v v = {0, 0, 0, 0, 0, 0, 0, 0};
    if (k < KC)
      v = *(const s8v*)(kvb + ((size_t)b * KC + k) * (2 * DDIM) + DDIM + h * DHD + c0);
#pragma unroll
    for (int j = 0; j < 8; j++) dbase[(size_t)j * BT_K + k] = (u16)v[j];
  }
}

// ---------------------------------------------------------------------------
// MFMA attention v3. 256 thr (4 waves), grid (17, H, B); wave w: rows +w*16.
//   Vt pre-transposed in global -> vector-staged LDS (conflict-free).
//   biasT fp32 [h][k][n] float4 loads fused in S loop; log2-domain softmax
//   (exp2f), normalization deferred to epilogue. P chunked through LDS.
// ---------------------------------------------------------------------------
#define VTS 328
#define PLS 72

__global__ __launch_bounds__(256) void attn_mfma(const u16* qb,
                                                 const u16* __restrict__ kvb,
                                                 const u16* __restrict__ vt,
                                                 const float* __restrict__ biasT,
                                                 u16* oh, u16* __restrict__ ol) {
  __shared__ u16 VtL[64 * VTS];
  __shared__ u16 PL[4][16 * PLS];
  const int tid = threadIdx.x;
  const int w = tid >> 6, l = tid & 63;
  const int lane16 = l & 15, quad = l >> 4;
  const int h = blockIdx.y, b = blockIdx.z;
  const int n_base = blockIdx.x * 64 + w * 16;

  // ---- stage Vt: 10x (b128 global load -> b128 LDS write) ----
  {
    const int c = tid >> 2;
    const int kq = (tid & 3) * 8;
    const u16* src = vt + (((size_t)b * HH + h) * 64 + c) * BT_K + kq;
    u16* dst = &VtL[c * VTS + kq];
#pragma unroll
    for (int it = 0; it < 10; it++)
      *(s8v*)(dst + it * 32) = *(const s8v*)(src + it * 32);
  }

  // ---- q fragments ----
  const int qrow = min(n_base + lane16, NN - 1);
  const u16* qp = qb + ((size_t)b * NN + qrow) * DDIM + h * DHD + quad * 8;
  const s8v qf0 = *(const s8v*)qp;
  const s8v qf1 = *(const s8v*)(qp + 32);

  // ---- S = QK^T fused with bias (log2 domain) ----
  f4v S[17];
  const float* bT = biasT + (size_t)h * BT_K * BT_N + (size_t)(n_base + quad * 4);
  float mx[4] = {-3.0e38f, -3.0e38f, -3.0e38f, -3.0e38f};
#pragma unroll
  for (int t = 0; t < 17; t++) {
    const int krow = min(t * 16 + lane16, KC - 1);
    const u16* kp = kvb + ((size_t)b * KC + krow) * (2 * DDIM) + h * DHD + quad * 8;
    const s8v kf0 = *(const s8v*)kp;
    const s8v kf1 = *(const s8v*)(kp + 32);
    f4v z = {0.f, 0.f, 0.f, 0.f};
    z = __builtin_amdgcn_mfma_f32_16x16x32_bf16(qf0, kf0, z, 0, 0, 0);
    z = __builtin_amdgcn_mfma_f32_16x16x32_bf16(qf1, kf1, z, 0, 0, 0);
    const float4 bv = *(const float4*)&bT[(size_t)(t * 16 + lane16) * BT_N];
    S[t][0] = fmaf(z[0], SCALE_LOG2E, bv.x);
    S[t][1] = fmaf(z[1], SCALE_LOG2E, bv.y);
    S[t][2] = fmaf(z[2], SCALE_LOG2E, bv.z);
    S[t][3] = fmaf(z[3], SCALE_LOG2E, bv.w);
#pragma unroll
    for (int r = 0; r < 4; r++) mx[r] = fmaxf(mx[r], S[t][r]);
  }
#pragma unroll
  for (int r = 0; r < 4; r++) {
    mx[r] = fmaxf(mx[r], __shfl_xor(mx[r], 1));
    mx[r] = fmaxf(mx[r], __shfl_xor(mx[r], 2));
    mx[r] = fmaxf(mx[r], __shfl_xor(mx[r], 4));
    mx[r] = fmaxf(mx[r], __shfl_xor(mx[r], 8));
  }
  float sm[4] = {0.f, 0.f, 0.f, 0.f};
#pragma unroll
  for (int t = 0; t < 17; t++)
#pragma unroll
    for (int r = 0; r < 4; r++) {
      const float p = exp2f(S[t][r] - mx[r]);  // unnormalized
      S[t][r] = p;
      sm[r] += p;
    }
#pragma unroll
  for (int r = 0; r < 4; r++) {
    sm[r] += __shfl_xor(sm[r], 1);
    sm[r] += __shfl_xor(sm[r], 2);
    sm[r] += __shfl_xor(sm[r], 4);
    sm[r] += __shfl_xor(sm[r], 8);
    sm[r] = 1.0f / sm[r];
  }

  f4v O[4];
#pragma unroll
  for (int nt = 0; nt < 4; nt++) O[nt] = (f4v){0.f, 0.f, 0.f, 0.f};

  __syncthreads();  // Vt staged

  u16* PLw = PL[w];
#pragma unroll
  for (int ch = 0; ch < 5; ch++) {
#pragma unroll
    for (int tt = 0; tt < 4; tt++) {
      const int t = ch * 4 + tt;
#pragma unroll
      for (int r = 0; r < 4; r++) {
        float pv = 0.f;
        if (t < 17) pv = S[t][r];
        PLw[(quad * 4 + r) * PLS + tt * 16 + lane16] = f2bf(pv);
      }
    }
    __syncthreads();
#pragma unroll
    for (int ks = 0; ks < 2; ks++) {
      const s8v a = *(const s8v*)&PLw[lane16 * PLS + ks * 32 + quad * 8];
#pragma unroll
      for (int nt = 0; nt < 4; nt++) {
        const s8v bfr =
            *(const s8v*)&VtL[(nt * 16 + lane16) * VTS + ch * 64 + ks * 32 + quad * 8];
        O[nt] = __builtin_amdgcn_mfma_f32_16x16x32_bf16(a, bfr, O[nt], 0, 0, 0);
      }
    }
    __syncthreads();
  }

  // ---- epilogue: normalize + split-store (hi/lo bf16) ----
#pragma unroll
  for (int nt = 0; nt < 4; nt++)
#pragma unroll
    for (int r = 0; r < 4; r++) {
      const int n = n_base + quad * 4 + r;
      if (n < NN) {
        const size_t idx = ((size_t)b * NN + n) * DDIM + h * DHD + nt * 16 + lane16;
        const float v = O[nt][r] * sm[r];
        const u16 hb = f2bf(v);
        oh[idx] = hb;
        ol[idx] = f2bf(v - bf2f(hb));
      }
    }
}

// ---------------------------------------------------------------------------
extern "C" void kernel_launch(void* const* d_in, const int* in_sizes, int n_in,
                              void* d_out, int out_size, void* d_ws, size_t ws_size,
                              hipStream_t stream) {
  (void)in_sizes; (void)n_in; (void)out_size; (void)ws_size;
  const float* x    = (const float*)d_in[0];
  const float* wlog = (const float*)d_in[1];
  const float* Wq   = (const float*)d_in[2];
  const float* Wkv  = (const float*)d_in[3];
  const float* Wo   = (const float*)d_in[4];
  const float* bo   = (const float*)d_in[5];
  const float* w1   = (const float*)d_in[6];
  const float* b1   = (const float*)d_in[7];
  const float* w2   = (const float*)d_in[8];
  const float* b2   = (const float*)d_in[9];
  const float* feats = (const float*)d_in[10];
  const float* mask  = (const float*)d_in[11];
  float* out = (float*)d_out;

  u8* p = (u8*)d_ws;
  u16* xb    = (u16*)(p + 0);             // 50,380,800 B (later o_lo)
  u16* ctxb  = (u16*)(p + 50380800);      // 12,632,064
  u16* Wqb   = (u16*)(p + 63012864);      //  1,179,648
  u16* Wkvb  = (u16*)(p + 64192512);      //  2,359,296
  u16* Woh   = (u16*)(p + 66551808);      //  1,179,648
  u16* Wol   = (u16*)(p + 67731456);      //  1,179,648
  u16* qb    = (u16*)(p + 68911104);      // 50,380,800 (later o_hi)
  u16* kvb   = (u16*)(p + 119291904);     // 25,264,128
  u16* vt    = (u16*)(p + 144556032);     // 15,728,640  [B][H][64][320]
  float* biasT = (float*)(p + 160284672); // 16,711,680  [H][320][1088] -> ~177 MB

  const int nx8 = (BB * NN * DDIM) / 8;
  cast_bf16_kernel<<<dim3((nx8 + 255) / 256), dim3(256), 0, stream>>>(x, xb, nx8);
  cast_bf16_kernel<<<dim3(288), dim3(256), 0, stream>>>(Wq, Wqb, (DDIM * DDIM) / 8);
  cast_bf16_kernel<<<dim3(576), dim3(256), 0, stream>>>(Wkv, Wkvb, (2 * DDIM * DDIM) / 8);
  split_bf16_kernel<<<dim3(288), dim3(256), 0, stream>>>(Wo, Woh, Wol, (DDIM * DDIM) / 8);
  pool_ctx_kernel<<<dim3(BB * KC), dim3(64), 0, stream>>>(x, wlog, ctxb);
  cpb_biasT_kernel<<<dim3((BT_K * BT_N) / 256), dim3(256), 0, stream>>>(
      feats, mask, w1, b1, w2, b2, biasT);
  gemm_mfma<0, 1, 0><<<dim3(257, 6), dim3(256), 0, stream>>>(
      xb, nullptr, Wqb, nullptr, nullptr, nullptr, qb, BB * NN, DDIM);
  gemm_mfma<0, 1, 0><<<dim3(65, 12), dim3(256), 0, stream>>>(
      ctxb, nullptr, Wkvb, nullptr, nullptr, nullptr, kvb, BB * KC, 2 * DDIM);
  transpose_v_kernel<<<dim3(BB * HH), dim3(256), 0, stream>>>(kvb, vt);
  attn_mfma<<<dim3(17, HH, BB), dim3(256), 0, stream>>>(qb, kvb, vt, biasT, qb, xb);
  gemm_mfma<1, 0, 1><<<dim3(257, 12), dim3(256), 0, stream>>>(
      qb, xb, Woh, Wol, bo, out, nullptr, BB * NN, DDIM);
}